// Round 6
// baseline (225.750 us; speedup 1.0000x reference)
//
#include <hip/hip_runtime.h>
#include <hip/hip_bf16.h>

#define B_ 32
#define T_ 2048
#define H_ 1024
#define S_ 8
#define V_ 32768
#define ROWS 256    // B_*S_
#define OUTO 8192   // S_*H_
#define NCHUNK 64
#define TCHUNK 32
#define NCB 256     // dist col-blocks = V_/128

typedef __attribute__((ext_vector_type(8))) short s16x8;
typedef __attribute__((ext_vector_type(8))) unsigned short u16x8;
typedef __attribute__((ext_vector_type(4))) float f32x4;

// async global->LDS, 16B per lane (dest = wave-uniform base + lane*16)
__device__ __forceinline__ void gl_lds16(const void* gsrc, void* ldst) {
  __builtin_amdgcn_global_load_lds(
      (const __attribute__((address_space(1))) unsigned int*)gsrc,
      (__attribute__((address_space(3))) unsigned int*)ldst, 16, 0, 0);
}

// bf16 split: x ~= hi + lo (RNE hi, RNE lo). Native casts -> v_cvt_pk_bf16_f32.
__device__ __forceinline__ void bsplit(float x, unsigned short& h, unsigned short& s) {
  __hip_bfloat16 hb = __float2bfloat16(x);
  float hf = __bfloat162float(hb);
  float lo = x - hf;
  __hip_bfloat16 lb = __float2bfloat16(lo);
  h = __builtin_bit_cast(unsigned short, hb);
  s = __builtin_bit_cast(unsigned short, lb);
}

// ---------------- kernel 1: masked pooling partials ----------------
__global__ void pool_kernel(const float* __restrict__ hidden,
                            const int* __restrict__ mask,
                            float* __restrict__ part_pool,   // [NCHUNK][B_][H_]
                            int* __restrict__ cntpart) {     // [NCHUNK][B_]
  int b = blockIdx.x;
  int chunk = blockIdx.y;
  int t0 = chunk * TCHUNK;
  int h4 = threadIdx.x * 4;
  const float* base = hidden + ((size_t)b * T_ + t0) * H_ + h4;
  const int* mrow = mask + (size_t)b * T_ + t0;
  float a0 = 0.f, a1 = 0.f, a2 = 0.f, a3 = 0.f;
  int mcount = 0;
#pragma unroll 4
  for (int i = 0; i < TCHUNK; ++i) {
    int mi = mrow[i];
    float m = (float)mi;
    mcount += mi;
    float4 v = *reinterpret_cast<const float4*>(base + (size_t)i * H_);
    a0 += m * v.x; a1 += m * v.y; a2 += m * v.z; a3 += m * v.w;
  }
  float* pp = part_pool + ((size_t)chunk * B_ + b) * H_ + h4;
  *reinterpret_cast<float4*>(pp) = make_float4(a0, a1, a2, a3);
  if (threadIdx.x == 0) cntpart[chunk * B_ + b] = mcount;
}

// ---------------- kernel 1b: reduce partials -> pooledT [h][b] ----------------
__global__ void pool_reduce_kernel(const float* __restrict__ part_pool,
                                   const int* __restrict__ cntpart,
                                   float* __restrict__ pooledT,
                                   int* __restrict__ cnt) {
  int g = blockIdx.x * 256 + threadIdx.x;   // g = b*1024 + h
  float s = 0.f;
  for (int c = 0; c < NCHUNK; ++c) s += part_pool[(size_t)c * (H_ * B_) + g];
  int b = g >> 10, h = g & 1023;
  pooledT[h * B_ + b] = s;
  if (g < B_) {
    int cs = 0;
    for (int c = 0; c < NCHUNK; ++c) cs += cntpart[c * B_ + g];
    cnt[g] = cs;
  }
}

// ---------------- kernel 2: pre_q = pooled @ W^T ----------------
__global__ void proj_kernel(const float* __restrict__ Wp,
                            const float* __restrict__ pooledT,
                            const int* __restrict__ cnt,
                            float* __restrict__ preq) {
  int t = threadIdx.x;
  int olocal = t >> 5;
  int o = blockIdx.x * 8 + olocal;
  int b = t & 31;
  const float* wrow = Wp + (size_t)o * H_;
  float acc = 0.f;
#pragma unroll 4
  for (int k = 0; k < H_; k += 4) {
    float4 w4 = *reinterpret_cast<const float4*>(wrow + k);
    float p0 = pooledT[(k + 0) * B_ + b];
    float p1 = pooledT[(k + 1) * B_ + b];
    float p2 = pooledT[(k + 2) * B_ + b];
    float p3 = pooledT[(k + 3) * B_ + b];
    acc += w4.x * p0 + w4.y * p1 + w4.z * p2 + w4.w * p3;
  }
  float denom = fmaxf((float)cnt[b], 1.0f);
  float val = acc / denom;
  __shared__ float xch[8][32];
  xch[olocal][b] = val;
  __syncthreads();
  int b2 = t >> 3, j = t & 7;
  preq[(size_t)b2 * OUTO + blockIdx.x * 8 + j] = xch[j][b2];
}

// ---------------- kernel 2b: split preq into swizzled MFMA bf16 image + xnorm ----------------
// A_img (ushort): [ks 0..31] { hi[256][32], lo[256][32] }, XOR-swizzled:
// ushort_idx ^= (row&7)<<3. dist reads with the same XOR (bijective; verified R5).
__global__ void aprep_kernel(const float* __restrict__ preq,
                             unsigned short* __restrict__ A_img,
                             float* __restrict__ xnorm) {
  int row = blockIdx.x;
  int t = threadIdx.x;
  int k0 = 4 * t;
  int ks = k0 >> 5, kk = k0 & 31;
  float4 v = reinterpret_cast<const float4*>(preq + (size_t)row * H_)[t];
  float xv[4] = {v.x, v.y, v.z, v.w};
  unsigned short hv[4], lv[4];
  float s = 0.f;
#pragma unroll
  for (int i = 0; i < 4; ++i) { s += xv[i] * xv[i]; bsplit(xv[i], hv[i], lv[i]); }
  unsigned int sidx = (unsigned int)(row * 32 + kk) ^ (unsigned int)((row & 7) << 3);
  size_t base = (size_t)ks * 16384 + sidx;
  *reinterpret_cast<ushort4*>(&A_img[base])        = make_ushort4(hv[0], hv[1], hv[2], hv[3]);
  *reinterpret_cast<ushort4*>(&A_img[base + 8192]) = make_ushort4(lv[0], lv[1], lv[2], lv[3]);
#pragma unroll
  for (int off = 1; off < 64; off <<= 1) s += __shfl_xor(s, off);
  __shared__ float ps[4];
  if ((t & 63) == 0) ps[t >> 6] = s;
  __syncthreads();
  if (t == 0) xnorm[row] = ps[0] + ps[1] + ps[2] + ps[3];
}

// ---------------- kernel 3: split-bf16 MFMA distance GEMM (counted-vmcnt pipeline) ----------------
// BM=256, BN=128, BK=32; 512 threads = 8 waves, grid 256 = 1 block/CU.
// T4: raw s_barrier + manual s_waitcnt vmcnt(2) -> codebook loads (2-step-deep prefetch,
// ra/rb rotation) stay in flight across barriers; only A-staging gl_lds drained per step.
// MFMA product-major (hh all, hl all, lh all) -> no dependent back-to-back MFMAs.
// Per-wave VMEM FIFO per step: [4 gl_lds][2 cb loads]; sched_barrier(0) pins the order.
__global__ __launch_bounds__(512, 2) void dist_kernel(
    const unsigned short* __restrict__ A_img, const float* __restrict__ codebook,
    const float* __restrict__ xnorm, float* __restrict__ logits,
    float* __restrict__ pscore, int* __restrict__ pidx) {
  __shared__ __align__(16) unsigned short Asm[2][16384];    // 64 KB (swizzled image)
  __shared__ __align__(16) unsigned short Bs[2][2][128][40];// 40 KB
  __shared__ float cn[128];
  __shared__ float xns[256];
  __shared__ float bwv[2][256];
  __shared__ int   bwi[2][256];

  const int t = threadIdx.x;        // 0..511
  const int l = t & 63;
  const int w = t >> 6;             // wave 0..7
  const int cb = w & 1;             // col half
  const int m0 = (w >> 1) * 64;     // row group
  const int lr = l & 15, lq = l >> 4;
  const int blk = blockIdx.x;
  const int v0 = blk * 128;

  if (t < 256) xns[t] = xnorm[t];

  const int sn = t >> 2;            // staged codebook row 0..127
  const int sk = (t & 3) * 8;       // k offset within 32
  const float* cbp = codebook + (size_t)(v0 + sn) * H_ + sk;
  float csq = 0.f;

  f32x4 acc[4][4];
#pragma unroll
  for (int i = 0; i < 4; ++i)
#pragma unroll
    for (int j = 0; j < 4; ++j) acc[i][j] = (f32x4){0.f, 0.f, 0.f, 0.f};

  const char* Abase = (const char*)A_img;

  // per-thread swizzled A read offsets (ushort units)
  unsigned int aoff[4];
#pragma unroll
  for (int mt = 0; mt < 4; ++mt) {
    int row = m0 + mt * 16 + lr;
    aoff[mt] = (unsigned int)(row * 32 + lq * 8) ^ (unsigned int)((row & 7) << 3);
  }

#define CONVERT_TO(BUF, X0, X1)                                                   \
  {                                                                               \
    float xv[8] = {X0.x, X0.y, X0.z, X0.w, X1.x, X1.y, X1.z, X1.w};               \
    u16x8 hv, lv;                                                                 \
    _Pragma("unroll")                                                             \
    for (int i = 0; i < 8; ++i) {                                                 \
      float x = xv[i];                                                            \
      csq += x * x;                                                               \
      unsigned short hh, ll;                                                      \
      bsplit(x, hh, ll);                                                          \
      hv[i] = hh; lv[i] = ll;                                                     \
    }                                                                             \
    *reinterpret_cast<u16x8*>(&Bs[BUF][0][sn][sk]) = hv;                          \
    *reinterpret_cast<u16x8*>(&Bs[BUF][1][sn][sk]) = lv;                          \
  }

#define READ_FRAGS(CURB)                                                          \
  _Pragma("unroll")                                                               \
  for (int mt = 0; mt < 4; ++mt) {                                                \
    const unsigned short* p = &Asm[CURB][aoff[mt]];                               \
    ah[mt] = *reinterpret_cast<const s16x8*>(p);                                  \
    al[mt] = *reinterpret_cast<const s16x8*>(p + 8192);                           \
  }                                                                               \
  _Pragma("unroll")                                                               \
  for (int nt = 0; nt < 4; ++nt) {                                                \
    bh[nt] = *reinterpret_cast<const s16x8*>(&Bs[CURB][0][cb*64 + nt*16 + lr][lq*8]); \
    bl[nt] = *reinterpret_cast<const s16x8*>(&Bs[CURB][1][cb*64 + nt*16 + lr][lq*8]); \
  }

#define MFMA_BLOCK                                                                \
  __builtin_amdgcn_s_setprio(1);                                                  \
  _Pragma("unroll")                                                               \
  for (int mt = 0; mt < 4; ++mt)                                                  \
    _Pragma("unroll")                                                             \
    for (int nt = 0; nt < 4; ++nt)                                                \
      acc[mt][nt] = __builtin_amdgcn_mfma_f32_16x16x32_bf16(ah[mt], bh[nt], acc[mt][nt], 0, 0, 0); \
  _Pragma("unroll")                                                               \
  for (int mt = 0; mt < 4; ++mt)                                                  \
    _Pragma("unroll")                                                             \
    for (int nt = 0; nt < 4; ++nt)                                                \
      acc[mt][nt] = __builtin_amdgcn_mfma_f32_16x16x32_bf16(ah[mt], bl[nt], acc[mt][nt], 0, 0, 0); \
  _Pragma("unroll")                                                               \
  for (int mt = 0; mt < 4; ++mt)                                                  \
    _Pragma("unroll")                                                             \
    for (int nt = 0; nt < 4; ++nt)                                                \
      acc[mt][nt] = __builtin_amdgcn_mfma_f32_16x16x32_bf16(al[mt], bh[nt], acc[mt][nt], 0, 0, 0); \
  __builtin_amdgcn_s_setprio(0);

#define STAGE_A(KS, BUF)                                                          \
  _Pragma("unroll")                                                               \
  for (int j = 0; j < 4; ++j) {                                                   \
    int c = w * 4 + j;                                                            \
    gl_lds16(Abase + (size_t)(KS) * 32768 + (size_t)c * 1024 + (size_t)l * 16,    \
             &Asm[BUF][c * 512]);                                                 \
  }

  // Steady-state step KS (0..29): stage A(KS+1); load cb(KS+2)->RT; MFMA(cur);
  // convert RS (=cb(KS+1)) -> Bs[nxt]; vmcnt(2) (keep cb(KS+2) in flight) + barrier.
#define DIST_STEP(KS, RT0, RT1, RS0, RS1)                                         \
  {                                                                               \
    const int curb = (KS) & 1, nxt = curb ^ 1;                                    \
    STAGE_A((KS) + 1, nxt);                                                       \
    __builtin_amdgcn_sched_barrier(0);                                            \
    RT0 = *reinterpret_cast<const float4*>(cbp + ((KS) + 2) * 32);                \
    RT1 = *reinterpret_cast<const float4*>(cbp + ((KS) + 2) * 32 + 4);            \
    __builtin_amdgcn_sched_barrier(0);                                            \
    s16x8 ah[4], al[4], bh[4], bl[4];                                             \
    READ_FRAGS(curb);                                                             \
    MFMA_BLOCK;                                                                   \
    CONVERT_TO(nxt, RS0, RS1);                                                    \
    __builtin_amdgcn_sched_barrier(0);                                            \
    asm volatile("s_waitcnt vmcnt(2) lgkmcnt(0)" ::: "memory");                   \
    __builtin_amdgcn_s_barrier();                                                 \
    __builtin_amdgcn_sched_barrier(0);                                            \
  }

  // ---- prologue: A(0) staged; cb(0)->ra, cb(1)->rb; convert cb(0)->Bs[0] ----
  STAGE_A(0, 0);
  __builtin_amdgcn_sched_barrier(0);
  float4 ra0 = *reinterpret_cast<const float4*>(cbp);
  float4 ra1 = *reinterpret_cast<const float4*>(cbp + 4);
  float4 rb0 = *reinterpret_cast<const float4*>(cbp + 32);
  float4 rb1 = *reinterpret_cast<const float4*>(cbp + 36);
  __builtin_amdgcn_sched_barrier(0);
  CONVERT_TO(0, ra0, ra1);          // compiler waits vmcnt(2): A(0)+cb(0) done, cb(1) in flight
  __builtin_amdgcn_sched_barrier(0);
  asm volatile("s_waitcnt vmcnt(2) lgkmcnt(0)" ::: "memory");
  __builtin_amdgcn_s_barrier();
  __builtin_amdgcn_sched_barrier(0);

  // ---- main loop: steps 0..29 (ra/rb rotate: even loads->ra, odd loads->rb) ----
  for (int ks = 0; ks < 30; ks += 2) {
    DIST_STEP(ks,     ra0, ra1, rb0, rb1);
    DIST_STEP(ks + 1, rb0, rb1, ra0, ra1);
  }

  // ---- peel step 30 (curb=0): stage A(31); no cb load; convert cb(31)=rb -> Bs[1] ----
  {
    STAGE_A(31, 1);
    __builtin_amdgcn_sched_barrier(0);
    s16x8 ah[4], al[4], bh[4], bl[4];
    READ_FRAGS(0);
    MFMA_BLOCK;
    CONVERT_TO(1, rb0, rb1);
    __builtin_amdgcn_sched_barrier(0);
    asm volatile("s_waitcnt vmcnt(0) lgkmcnt(0)" ::: "memory");
    __builtin_amdgcn_s_barrier();
    __builtin_amdgcn_sched_barrier(0);
  }
  // ---- peel step 31 (curb=1): compute only ----
  {
    s16x8 ah[4], al[4], bh[4], bl[4];
    READ_FRAGS(1);
    MFMA_BLOCK;
  }

  // ||c||^2: reduce the 4 k-offset threads (consecutive lanes) of each staged row
  csq += __shfl_xor(csq, 1);
  csq += __shfl_xor(csq, 2);
  if ((t & 3) == 0) cn[sn] = csq;
  __syncthreads();

  // epilogue: logits + per-row best over this block's 128 cols
  const float NEG = -3.402823466e38f;
#pragma unroll
  for (int mt = 0; mt < 4; ++mt) {
#pragma unroll
    for (int r = 0; r < 4; ++r) {
      int row = m0 + mt * 16 + lq * 4 + r;
      float xn = xns[row];
      float bs = NEG; int bix = 0;
#pragma unroll
      for (int nt = 0; nt < 4; ++nt) {
        int col = cb * 64 + nt * 16 + lr;
        float sc = 2.f * acc[mt][nt][r] - cn[col];
        logits[(size_t)row * V_ + v0 + col] = sc - xn;
        if (sc > bs) { bs = sc; bix = v0 + col; }   // nt ascending => first-max tie-break
      }
#pragma unroll
      for (int off = 1; off < 16; off <<= 1) {      // reduce within 16-lane (same-row) group
        float os = __shfl_xor(bs, off);
        int oi = __shfl_xor(bix, off);
        if (os > bs || (os == bs && oi < bix)) { bs = os; bix = oi; }
      }
      if (lr == 0) { bwv[cb][row] = bs; bwi[cb][row] = bix; }
    }
  }
  __syncthreads();
  if (t < 256) {
    float b0 = bwv[0][t]; int i0 = bwi[0][t];
    float b1 = bwv[1][t]; int i1 = bwi[1][t];
    if (b1 > b0 || (b1 == b0 && i1 < i0)) { b0 = b1; i0 = i1; }
    pscore[(size_t)t * NCB + blk] = b0;
    pidx[(size_t)t * NCB + blk] = i0;
  }
}

// ---------------- kernel 4: per-row argmax over blocks, gather, quantized, loss partial ----------------
__global__ void finalize_kernel(const float* __restrict__ preq,
                                const float* __restrict__ codebook,
                                const float* __restrict__ pscore,
                                const int* __restrict__ pidx,
                                float* __restrict__ out_idx,
                                float* __restrict__ out_quant,
                                float* __restrict__ lsum) {
  int row = blockIdx.x;
  int t = threadIdx.x;
  float bs = -3.402823466e38f; int bi = 0x7fffffff;
  for (int p = t; p < NCB; p += 256) {
    float s = pscore[(size_t)row * NCB + p];
    int ix = pidx[(size_t)row * NCB + p];
    if (s > bs || (s == bs && ix < bi)) { bs = s; bi = ix; }
  }
#pragma unroll
  for (int off = 1; off < 64; off <<= 1) {
    float os = __shfl_xor(bs, off);
    int oi = __shfl_xor(bi, off);
    if (os > bs || (os == bs && oi < bi)) { bs = os; bi = oi; }
  }
  __shared__ float ss[4]; __shared__ int si[4]; __shared__ int fidx;
  if ((t & 63) == 0) { ss[t >> 6] = bs; si[t >> 6] = bi; }
  __syncthreads();
  if (t == 0) {
    float b0 = ss[0]; int i0 = si[0];
    for (int wv = 1; wv < 4; ++wv)
      if (ss[wv] > b0 || (ss[wv] == b0 && si[wv] < i0)) { b0 = ss[wv]; i0 = si[wv]; }
    fidx = i0;
    out_idx[row] = (float)i0;
  }
  __syncthreads();
  int idx = fidx;
  float4 e = reinterpret_cast<const float4*>(codebook + (size_t)idx * H_)[t];
  float4 p = reinterpret_cast<const float4*>(preq + (size_t)row * H_)[t];
  float4 q;
  q.x = p.x + (e.x - p.x); q.y = p.y + (e.y - p.y);
  q.z = p.z + (e.z - p.z); q.w = p.w + (e.w - p.w);
  reinterpret_cast<float4*>(out_quant)[row * 256 + t] = q;
  float dx = p.x - e.x, dy = p.y - e.y, dz = p.z - e.z, dw = p.w - e.w;
  float ls = dx * dx + dy * dy + dz * dz + dw * dw;
#pragma unroll
  for (int off = 1; off < 64; off <<= 1) ls += __shfl_xor(ls, off);
  __shared__ float lss[4];
  if ((t & 63) == 0) lss[t >> 6] = ls;
  __syncthreads();
  if (t == 0) lsum[row] = lss[0] + lss[1] + lss[2] + lss[3];
}

// ---------------- kernel 5: final losses ----------------
__global__ void loss_kernel(const float* __restrict__ lsum, float* __restrict__ out_loss) {
  int t = threadIdx.x;
  float s = lsum[t];
#pragma unroll
  for (int off = 1; off < 64; off <<= 1) s += __shfl_xor(s, off);
  __shared__ float a[4];
  if ((t & 63) == 0) a[t >> 6] = s;
  __syncthreads();
  if (t == 0) {
    float lv = (a[0] + a[1] + a[2] + a[3]) / (float)(ROWS * H_);
    out_loss[0] = lv; out_loss[1] = lv;
  }
}

extern "C" void kernel_launch(void* const* d_in, const int* in_sizes, int n_in,
                              void* d_out, int out_size, void* d_ws, size_t ws_size,
                              hipStream_t stream) {
  (void)in_sizes; (void)n_in; (void)out_size; (void)ws_size;
  const float* hidden   = (const float*)d_in[0];
  const int* mask       = (const int*)d_in[1];
  const float* Wp       = (const float*)d_in[2];
  const float* codebook = (const float*)d_in[3];

  float* out = (float*)d_out;
  float* out_logits = out;                        // 8388608
  float* out_idx    = out + 8388608;              // 256
  float* out_preq   = out_idx + 256;              // 262144
  float* out_quant  = out_preq + 262144;          // 262144
  float* out_loss   = out_quant + 262144;         // 2

  // Early scratch inside logits region (fully overwritten by dist_kernel later).
  float* part_pool = out_logits;                   // 64*32*1024 = 2097152 floats
  int*   cntpart   = (int*)(out_logits + 2097152); // 2048
  float* pooledT   = out_logits + 2099200;         // 32768
  int*   cnt       = (int*)(out_logits + 2131968); // 32

  // d_ws scratch (~1.6 MB)
  float* ws     = (float*)d_ws;
  float* xnorm  = ws;                              // 256
  float* pscore = ws + 256;                        // 256*256
  int*   pidx   = (int*)(ws + 256 + 65536);        // 256*256
  float* lsum   = ws + 131328;                     // 256
  unsigned short* A_img = (unsigned short*)(ws + 131584);  // 1 MB

  pool_kernel<<<dim3(B_, NCHUNK), 256, 0, stream>>>(hidden, mask, part_pool, cntpart);
  pool_reduce_kernel<<<128, 256, 0, stream>>>(part_pool, cntpart, pooledT, cnt);
  proj_kernel<<<1024, 256, 0, stream>>>(Wp, pooledT, cnt, out_preq);
  aprep_kernel<<<ROWS, 256, 0, stream>>>(out_preq, A_img, xnorm);
  dist_kernel<<<NCB, 512, 0, stream>>>(A_img, codebook, xnorm, out_logits, pscore, pidx);
  finalize_kernel<<<ROWS, 256, 0, stream>>>(out_preq, codebook, pscore, pidx, out_idx, out_quant, lsum);
  loss_kernel<<<1, 256, 0, stream>>>(lsum, out_loss);
}

// Round 7
// 214.627 us; speedup vs baseline: 1.0518x; 1.0518x over previous
//
#include <hip/hip_runtime.h>
#include <hip/hip_bf16.h>

#define B_ 32
#define T_ 2048
#define H_ 1024
#define S_ 8
#define V_ 32768
#define ROWS 256    // B_*S_
#define OUTO 8192   // S_*H_
#define NCHUNK 64
#define TCHUNK 32
#define NCB 256     // dist col-blocks = V_/128

typedef __attribute__((ext_vector_type(8))) short s16x8;
typedef __attribute__((ext_vector_type(8))) unsigned short u16x8;
typedef __attribute__((ext_vector_type(4))) float f32x4;

// async global->LDS, 16B per lane (dest = wave-uniform base + lane*16)
__device__ __forceinline__ void gl_lds16(const void* gsrc, void* ldst) {
  __builtin_amdgcn_global_load_lds(
      (const __attribute__((address_space(1))) unsigned int*)gsrc,
      (__attribute__((address_space(3))) unsigned int*)ldst, 16, 0, 0);
}

// bf16 split: x ~= hi + lo (RNE hi, RNE lo)
__device__ __forceinline__ void bsplit(float x, unsigned short& h, unsigned short& s) {
  __hip_bfloat16 hb = __float2bfloat16(x);
  float hf = __bfloat162float(hb);
  float lo = x - hf;
  __hip_bfloat16 lb = __float2bfloat16(lo);
  h = __builtin_bit_cast(unsigned short, hb);
  s = __builtin_bit_cast(unsigned short, lb);
}

// ---------------- kernel 1: masked pooling partials ----------------
__global__ void pool_kernel(const float* __restrict__ hidden,
                            const int* __restrict__ mask,
                            float* __restrict__ part_pool,   // [NCHUNK][B_][H_]
                            int* __restrict__ cntpart) {     // [NCHUNK][B_]
  int b = blockIdx.x;
  int chunk = blockIdx.y;
  int t0 = chunk * TCHUNK;
  int h4 = threadIdx.x * 4;
  const float* base = hidden + ((size_t)b * T_ + t0) * H_ + h4;
  const int* mrow = mask + (size_t)b * T_ + t0;
  float a0 = 0.f, a1 = 0.f, a2 = 0.f, a3 = 0.f;
  int mcount = 0;
#pragma unroll 4
  for (int i = 0; i < TCHUNK; ++i) {
    int mi = mrow[i];
    float m = (float)mi;
    mcount += mi;
    float4 v = *reinterpret_cast<const float4*>(base + (size_t)i * H_);
    a0 += m * v.x; a1 += m * v.y; a2 += m * v.z; a3 += m * v.w;
  }
  float* pp = part_pool + ((size_t)chunk * B_ + b) * H_ + h4;
  *reinterpret_cast<float4*>(pp) = make_float4(a0, a1, a2, a3);
  if (threadIdx.x == 0) cntpart[chunk * B_ + b] = mcount;
}

// ---------------- kernel 1b: reduce partials -> pooledT [h][b] ----------------
__global__ void pool_reduce_kernel(const float* __restrict__ part_pool,
                                   const int* __restrict__ cntpart,
                                   float* __restrict__ pooledT,
                                   int* __restrict__ cnt) {
  int g = blockIdx.x * 256 + threadIdx.x;   // g = b*1024 + h
  float s = 0.f;
  for (int c = 0; c < NCHUNK; ++c) s += part_pool[(size_t)c * (H_ * B_) + g];
  int b = g >> 10, h = g & 1023;
  pooledT[h * B_ + b] = s;
  if (g < B_) {
    int cs = 0;
    for (int c = 0; c < NCHUNK; ++c) cs += cntpart[c * B_ + g];
    cnt[g] = cs;
  }
}

// ---------------- kernel 2: pre_q = pooled @ W^T (LDS-staged pooled, 4 o/thread) ----------------
// grid 256: block = 32 o-cols x 32 b. Pooled tile staged to LDS in [b][k] (pad 516,
// <=4-way banks); inner loop: 1 LDS b128 + 4 broadcast W float4 per 4-k step.
__global__ __launch_bounds__(256) void proj_kernel(const float* __restrict__ Wp,
                            const float* __restrict__ pooledT,
                            const int* __restrict__ cnt,
                            float* __restrict__ preq) {
  __shared__ float pl[32][516];
  const int t = threadIdx.x;
  const int og = t >> 5, b = t & 31;
  const int o0 = blockIdx.x * 32;
  float acc0 = 0.f, acc1 = 0.f, acc2 = 0.f, acc3 = 0.f;
  const float* wb = Wp + (size_t)(o0 + og * 4) * H_;
  for (int pass = 0; pass < 2; ++pass) {
    int k0 = pass * 512;
    __syncthreads();
#pragma unroll
    for (int i = 0; i < 16; ++i) {
      int f = i * 1024 + t * 4;            // 0..16383 over (k_local, b)
      int hl = f >> 5, b4 = f & 31;
      float4 v = *reinterpret_cast<const float4*>(&pooledT[(size_t)(k0 + hl) * 32 + b4]);
      pl[b4 + 0][hl] = v.x; pl[b4 + 1][hl] = v.y;
      pl[b4 + 2][hl] = v.z; pl[b4 + 3][hl] = v.w;
    }
    __syncthreads();
    const float* w0 = wb + k0;
#pragma unroll 4
    for (int j = 0; j < 128; ++j) {
      float4 p = *reinterpret_cast<const float4*>(&pl[b][4 * j]);
      float4 a = *reinterpret_cast<const float4*>(w0 + 4 * j);
      float4 c = *reinterpret_cast<const float4*>(w0 + H_ + 4 * j);
      float4 d = *reinterpret_cast<const float4*>(w0 + 2 * H_ + 4 * j);
      float4 e = *reinterpret_cast<const float4*>(w0 + 3 * H_ + 4 * j);
      acc0 += a.x * p.x + a.y * p.y + a.z * p.z + a.w * p.w;
      acc1 += c.x * p.x + c.y * p.y + c.z * p.z + c.w * p.w;
      acc2 += d.x * p.x + d.y * p.y + d.z * p.z + d.w * p.w;
      acc3 += e.x * p.x + e.y * p.y + e.z * p.z + e.w * p.w;
    }
  }
  float denom = fmaxf((float)cnt[b], 1.0f);
  size_t obase = (size_t)b * OUTO + o0 + og * 4;
  preq[obase + 0] = acc0 / denom;
  preq[obase + 1] = acc1 / denom;
  preq[obase + 2] = acc2 / denom;
  preq[obase + 3] = acc3 / denom;
}

// ---------------- kernel 2b: split preq into swizzled MFMA bf16 image + xnorm ----------------
// A_img (ushort): [ks 0..31] { hi[256][32], lo[256][32] }, XOR-swizzled:
// ushort_idx ^= (row&7)<<3. dist reads with the same XOR (bijective; verified R5).
__global__ void aprep_kernel(const float* __restrict__ preq,
                             unsigned short* __restrict__ A_img,
                             float* __restrict__ xnorm) {
  int row = blockIdx.x;
  int t = threadIdx.x;
  int k0 = 4 * t;
  int ks = k0 >> 5, kk = k0 & 31;
  float4 v = reinterpret_cast<const float4*>(preq + (size_t)row * H_)[t];
  float xv[4] = {v.x, v.y, v.z, v.w};
  unsigned short hv[4], lv[4];
  float s = 0.f;
#pragma unroll
  for (int i = 0; i < 4; ++i) { s += xv[i] * xv[i]; bsplit(xv[i], hv[i], lv[i]); }
  unsigned int sidx = (unsigned int)(row * 32 + kk) ^ (unsigned int)((row & 7) << 3);
  size_t base = (size_t)ks * 16384 + sidx;
  *reinterpret_cast<ushort4*>(&A_img[base])        = make_ushort4(hv[0], hv[1], hv[2], hv[3]);
  *reinterpret_cast<ushort4*>(&A_img[base + 8192]) = make_ushort4(lv[0], lv[1], lv[2], lv[3]);
#pragma unroll
  for (int off = 1; off < 64; off <<= 1) s += __shfl_xor(s, off);
  __shared__ float ps[4];
  if ((t & 63) == 0) ps[t >> 6] = s;
  __syncthreads();
  if (t == 0) xnorm[row] = ps[0] + ps[1] + ps[2] + ps[3];
}

// ---------------- kernel 3: split-bf16 MFMA distance GEMM (4-phase interleave) ----------------
// BM=256, BN=128, BK=32; 512 threads = 8 waves, grid 256 = 1 block/CU.
// T3+T4+T5: per K-step 4 phases {ds_read half ∥ stage -> s_barrier -> setprio+12 MFMA
// -> s_barrier}; gl_lds issued FIRST in VMEM FIFO, cb loads after, so end-of-step
// vmcnt(2) retires A-staging and keeps the 2-deep cb prefetch in flight.
__global__ __launch_bounds__(512, 2) void dist_kernel(
    const unsigned short* __restrict__ A_img, const float* __restrict__ codebook,
    const float* __restrict__ xnorm, float* __restrict__ logits,
    float* __restrict__ pscore, int* __restrict__ pidx) {
  __shared__ __align__(16) unsigned short Asm[2][16384];    // 64 KB (swizzled image)
  __shared__ __align__(16) unsigned short Bs[2][2][128][40];// 40 KB
  __shared__ float cn[128];
  __shared__ float xns[256];
  __shared__ float bwv[2][256];
  __shared__ int   bwi[2][256];

  const int t = threadIdx.x;        // 0..511
  const int l = t & 63;
  const int w = t >> 6;             // wave 0..7
  const int cb = w & 1;             // col half
  const int m0 = (w >> 1) * 64;     // row group
  const int lr = l & 15, lq = l >> 4;
  const int blk = blockIdx.x;
  const int v0 = blk * 128;

  if (t < 256) xns[t] = xnorm[t];

  const int sn = t >> 2;            // staged codebook row 0..127
  const int sk = (t & 3) * 8;       // k offset within 32
  const float* cbp = codebook + (size_t)(v0 + sn) * H_ + sk;
  float csq = 0.f;

  f32x4 acc[4][4];
#pragma unroll
  for (int i = 0; i < 4; ++i)
#pragma unroll
    for (int j = 0; j < 4; ++j) acc[i][j] = (f32x4){0.f, 0.f, 0.f, 0.f};

  const char* Abase = (const char*)A_img;

  // per-thread swizzled A read offsets (ushort units)
  unsigned int aoff[4];
#pragma unroll
  for (int mt = 0; mt < 4; ++mt) {
    int row = m0 + mt * 16 + lr;
    aoff[mt] = (unsigned int)(row * 32 + lq * 8) ^ (unsigned int)((row & 7) << 3);
  }

#define CONVERT_TO(BUF, X0, X1)                                                   \
  {                                                                               \
    float xv[8] = {X0.x, X0.y, X0.z, X0.w, X1.x, X1.y, X1.z, X1.w};               \
    u16x8 hv, lv;                                                                 \
    _Pragma("unroll")                                                             \
    for (int i = 0; i < 8; ++i) {                                                 \
      float x = xv[i];                                                            \
      csq += x * x;                                                               \
      unsigned short hh, ll;                                                      \
      bsplit(x, hh, ll);                                                          \
      hv[i] = hh; lv[i] = ll;                                                     \
    }                                                                             \
    *reinterpret_cast<u16x8*>(&Bs[BUF][0][sn][sk]) = hv;                          \
    *reinterpret_cast<u16x8*>(&Bs[BUF][1][sn][sk]) = lv;                          \
  }

#define READ_A2(CURB, M0, M1)                                                     \
  {                                                                               \
    const unsigned short* p0 = &Asm[CURB][aoff[M0]];                              \
    ah[M0] = *reinterpret_cast<const s16x8*>(p0);                                 \
    al[M0] = *reinterpret_cast<const s16x8*>(p0 + 8192);                          \
    const unsigned short* p1 = &Asm[CURB][aoff[M1]];                              \
    ah[M1] = *reinterpret_cast<const s16x8*>(p1);                                 \
    al[M1] = *reinterpret_cast<const s16x8*>(p1 + 8192);                          \
  }

#define READ_B2(CURB, N0, N1)                                                     \
  bh[N0] = *reinterpret_cast<const s16x8*>(&Bs[CURB][0][cb*64 + (N0)*16 + lr][lq*8]); \
  bl[N0] = *reinterpret_cast<const s16x8*>(&Bs[CURB][1][cb*64 + (N0)*16 + lr][lq*8]); \
  bh[N1] = *reinterpret_cast<const s16x8*>(&Bs[CURB][0][cb*64 + (N1)*16 + lr][lq*8]); \
  bl[N1] = *reinterpret_cast<const s16x8*>(&Bs[CURB][1][cb*64 + (N1)*16 + lr][lq*8]);

#define MFMA12(M0, M1, N0, N1)                                                    \
  __builtin_amdgcn_s_setprio(1);                                                  \
  acc[M0][N0] = __builtin_amdgcn_mfma_f32_16x16x32_bf16(ah[M0], bh[N0], acc[M0][N0], 0, 0, 0); \
  acc[M0][N1] = __builtin_amdgcn_mfma_f32_16x16x32_bf16(ah[M0], bh[N1], acc[M0][N1], 0, 0, 0); \
  acc[M1][N0] = __builtin_amdgcn_mfma_f32_16x16x32_bf16(ah[M1], bh[N0], acc[M1][N0], 0, 0, 0); \
  acc[M1][N1] = __builtin_amdgcn_mfma_f32_16x16x32_bf16(ah[M1], bh[N1], acc[M1][N1], 0, 0, 0); \
  acc[M0][N0] = __builtin_amdgcn_mfma_f32_16x16x32_bf16(ah[M0], bl[N0], acc[M0][N0], 0, 0, 0); \
  acc[M0][N1] = __builtin_amdgcn_mfma_f32_16x16x32_bf16(ah[M0], bl[N1], acc[M0][N1], 0, 0, 0); \
  acc[M1][N0] = __builtin_amdgcn_mfma_f32_16x16x32_bf16(ah[M1], bl[N0], acc[M1][N0], 0, 0, 0); \
  acc[M1][N1] = __builtin_amdgcn_mfma_f32_16x16x32_bf16(ah[M1], bl[N1], acc[M1][N1], 0, 0, 0); \
  acc[M0][N0] = __builtin_amdgcn_mfma_f32_16x16x32_bf16(al[M0], bh[N0], acc[M0][N0], 0, 0, 0); \
  acc[M0][N1] = __builtin_amdgcn_mfma_f32_16x16x32_bf16(al[M0], bh[N1], acc[M0][N1], 0, 0, 0); \
  acc[M1][N0] = __builtin_amdgcn_mfma_f32_16x16x32_bf16(al[M1], bh[N0], acc[M1][N0], 0, 0, 0); \
  acc[M1][N1] = __builtin_amdgcn_mfma_f32_16x16x32_bf16(al[M1], bh[N1], acc[M1][N1], 0, 0, 0); \
  __builtin_amdgcn_s_setprio(0);

#define STAGE_A(KS, BUF)                                                          \
  _Pragma("unroll")                                                               \
  for (int j = 0; j < 4; ++j) {                                                   \
    int c = w * 4 + j;                                                            \
    gl_lds16(Abase + (size_t)(KS) * 32768 + (size_t)c * 1024 + (size_t)l * 16,    \
             &Asm[BUF][c * 512]);                                                 \
  }

  // Steady-state step (ks = 0..29): 4 phases.
#define DIST_STEP4(KS, RT0, RT1, RS0, RS1)                                        \
  {                                                                               \
    const int curb = (KS) & 1, nxt = curb ^ 1;                                    \
    s16x8 ah[4], al[4], bh[4], bl[4];                                             \
    /* P1: half frags + stage A (gl_lds FIRST in FIFO) + cb prefetch */           \
    READ_A2(curb, 0, 1); READ_B2(curb, 0, 1);                                     \
    STAGE_A((KS) + 1, nxt);                                                       \
    RT0 = *reinterpret_cast<const float4*>(cbp + ((KS) + 2) * 32);                \
    RT1 = *reinterpret_cast<const float4*>(cbp + ((KS) + 2) * 32 + 4);            \
    __builtin_amdgcn_s_barrier();                                                 \
    MFMA12(0, 1, 0, 1);                                                           \
    __builtin_amdgcn_s_barrier();                                                 \
    /* P2: other half frags */                                                    \
    READ_A2(curb, 2, 3); READ_B2(curb, 2, 3);                                     \
    __builtin_amdgcn_s_barrier();                                                 \
    MFMA12(0, 1, 2, 3);                                                           \
    __builtin_amdgcn_s_barrier();                                                 \
    /* P3: convert next-step B into alternate buffer */                           \
    CONVERT_TO(nxt, RS0, RS1);                                                    \
    __builtin_amdgcn_s_barrier();                                                 \
    MFMA12(2, 3, 0, 1);                                                           \
    __builtin_amdgcn_s_barrier();                                                 \
    /* P4: finish; retire gl_lds, keep 2 cb loads in flight */                    \
    MFMA12(2, 3, 2, 3);                                                           \
    asm volatile("s_waitcnt vmcnt(2) lgkmcnt(0)" ::: "memory");                   \
    __builtin_amdgcn_s_barrier();                                                 \
    __builtin_amdgcn_sched_barrier(0);                                            \
  }

  // ---- prologue: A(0) staged; cb(0)->ra, cb(1)->rb; convert cb(0)->Bs[0] ----
  STAGE_A(0, 0);
  float4 ra0 = *reinterpret_cast<const float4*>(cbp);
  float4 ra1 = *reinterpret_cast<const float4*>(cbp + 4);
  float4 rb0 = *reinterpret_cast<const float4*>(cbp + 32);
  float4 rb1 = *reinterpret_cast<const float4*>(cbp + 36);
  CONVERT_TO(0, ra0, ra1);
  asm volatile("s_waitcnt vmcnt(2) lgkmcnt(0)" ::: "memory");
  __builtin_amdgcn_s_barrier();
  __builtin_amdgcn_sched_barrier(0);

  // ---- main loop: steps 0..29 ----
#pragma unroll 1
  for (int ks = 0; ks < 30; ks += 2) {
    DIST_STEP4(ks,     ra0, ra1, rb0, rb1);
    DIST_STEP4(ks + 1, rb0, rb1, ra0, ra1);
  }

  // ---- peel step 30 (curb=0): stage A(31); no cb load; convert cb(31)=rb -> Bs[1] ----
  {
    s16x8 ah[4], al[4], bh[4], bl[4];
    READ_A2(0, 0, 1); READ_B2(0, 0, 1);
    STAGE_A(31, 1);
    __builtin_amdgcn_s_barrier();
    MFMA12(0, 1, 0, 1);
    __builtin_amdgcn_s_barrier();
    READ_A2(0, 2, 3); READ_B2(0, 2, 3);
    __builtin_amdgcn_s_barrier();
    MFMA12(0, 1, 2, 3);
    __builtin_amdgcn_s_barrier();
    CONVERT_TO(1, rb0, rb1);
    __builtin_amdgcn_s_barrier();
    MFMA12(2, 3, 0, 1);
    __builtin_amdgcn_s_barrier();
    MFMA12(2, 3, 2, 3);
    asm volatile("s_waitcnt vmcnt(0) lgkmcnt(0)" ::: "memory");
    __builtin_amdgcn_s_barrier();
    __builtin_amdgcn_sched_barrier(0);
  }
  // ---- peel step 31 (curb=1): compute only ----
  {
    s16x8 ah[4], al[4], bh[4], bl[4];
    READ_A2(1, 0, 1); READ_B2(1, 0, 1);
    __builtin_amdgcn_s_barrier();
    MFMA12(0, 1, 0, 1);
    __builtin_amdgcn_s_barrier();
    READ_A2(1, 2, 3); READ_B2(1, 2, 3);
    MFMA12(0, 1, 2, 3);
    MFMA12(2, 3, 0, 1);
    MFMA12(2, 3, 2, 3);
  }

  // ||c||^2: reduce the 4 k-offset threads (consecutive lanes) of each staged row
  csq += __shfl_xor(csq, 1);
  csq += __shfl_xor(csq, 2);
  if ((t & 3) == 0) cn[sn] = csq;
  __syncthreads();

  // epilogue: logits + per-row best over this block's 128 cols
  const float NEG = -3.402823466e38f;
#pragma unroll
  for (int mt = 0; mt < 4; ++mt) {
#pragma unroll
    for (int r = 0; r < 4; ++r) {
      int row = m0 + mt * 16 + lq * 4 + r;
      float xn = xns[row];
      float bs = NEG; int bix = 0;
#pragma unroll
      for (int nt = 0; nt < 4; ++nt) {
        int col = cb * 64 + nt * 16 + lr;
        float sc = 2.f * acc[mt][nt][r] - cn[col];
        logits[(size_t)row * V_ + v0 + col] = sc - xn;
        if (sc > bs) { bs = sc; bix = v0 + col; }   // nt ascending => first-max tie-break
      }
#pragma unroll
      for (int off = 1; off < 16; off <<= 1) {      // reduce within 16-lane (same-row) group
        float os = __shfl_xor(bs, off);
        int oi = __shfl_xor(bix, off);
        if (os > bs || (os == bs && oi < bix)) { bs = os; bix = oi; }
      }
      if (lr == 0) { bwv[cb][row] = bs; bwi[cb][row] = bix; }
    }
  }
  __syncthreads();
  if (t < 256) {
    float b0 = bwv[0][t]; int i0 = bwi[0][t];
    float b1 = bwv[1][t]; int i1 = bwi[1][t];
    if (b1 > b0 || (b1 == b0 && i1 < i0)) { b0 = b1; i0 = i1; }
    pscore[(size_t)t * NCB + blk] = b0;
    pidx[(size_t)t * NCB + blk] = i0;
  }
}

// ---------------- kernel 4: per-row argmax over blocks, gather, quantized, loss partial ----------------
__global__ void finalize_kernel(const float* __restrict__ preq,
                                const float* __restrict__ codebook,
                                const float* __restrict__ pscore,
                                const int* __restrict__ pidx,
                                float* __restrict__ out_idx,
                                float* __restrict__ out_quant,
                                float* __restrict__ lsum) {
  int row = blockIdx.x;
  int t = threadIdx.x;
  float bs = -3.402823466e38f; int bi = 0x7fffffff;
  for (int p = t; p < NCB; p += 256) {
    float s = pscore[(size_t)row * NCB + p];
    int ix = pidx[(size_t)row * NCB + p];
    if (s > bs || (s == bs && ix < bi)) { bs = s; bi = ix; }
  }
#pragma unroll
  for (int off = 1; off < 64; off <<= 1) {
    float os = __shfl_xor(bs, off);
    int oi = __shfl_xor(bi, off);
    if (os > bs || (os == bs && oi < bi)) { bs = os; bi = oi; }
  }
  __shared__ float ss[4]; __shared__ int si[4]; __shared__ int fidx;
  if ((t & 63) == 0) { ss[t >> 6] = bs; si[t >> 6] = bi; }
  __syncthreads();
  if (t == 0) {
    float b0 = ss[0]; int i0 = si[0];
    for (int wv = 1; wv < 4; ++wv)
      if (ss[wv] > b0 || (ss[wv] == b0 && si[wv] < i0)) { b0 = ss[wv]; i0 = si[wv]; }
    fidx = i0;
    out_idx[row] = (float)i0;
  }
  __syncthreads();
  int idx = fidx;
  float4 e = reinterpret_cast<const float4*>(codebook + (size_t)idx * H_)[t];
  float4 p = reinterpret_cast<const float4*>(preq + (size_t)row * H_)[t];
  float4 q;
  q.x = p.x + (e.x - p.x); q.y = p.y + (e.y - p.y);
  q.z = p.z + (e.z - p.z); q.w = p.w + (e.w - p.w);
  reinterpret_cast<float4*>(out_quant)[row * 256 + t] = q;
  float dx = p.x - e.x, dy = p.y - e.y, dz = p.z - e.z, dw = p.w - e.w;
  float ls = dx * dx + dy * dy + dz * dz + dw * dw;
#pragma unroll
  for (int off = 1; off < 64; off <<= 1) ls += __shfl_xor(ls, off);
  __shared__ float lss[4];
  if ((t & 63) == 0) lss[t >> 6] = ls;
  __syncthreads();
  if (t == 0) lsum[row] = lss[0] + lss[1] + lss[2] + lss[3];
}

// ---------------- kernel 5: final losses ----------------
__global__ void loss_kernel(const float* __restrict__ lsum, float* __restrict__ out_loss) {
  int t = threadIdx.x;
  float s = lsum[t];
#pragma unroll
  for (int off = 1; off < 64; off <<= 1) s += __shfl_xor(s, off);
  __shared__ float a[4];
  if ((t & 63) == 0) a[t >> 6] = s;
  __syncthreads();
  if (t == 0) {
    float lv = (a[0] + a[1] + a[2] + a[3]) / (float)(ROWS * H_);
    out_loss[0] = lv; out_loss[1] = lv;
  }
}

extern "C" void kernel_launch(void* const* d_in, const int* in_sizes, int n_in,
                              void* d_out, int out_size, void* d_ws, size_t ws_size,
                              hipStream_t stream) {
  (void)in_sizes; (void)n_in; (void)out_size; (void)ws_size;
  const float* hidden   = (const float*)d_in[0];
  const int* mask       = (const int*)d_in[1];
  const float* Wp       = (const float*)d_in[2];
  const float* codebook = (const float*)d_in[3];

  float* out = (float*)d_out;
  float* out_logits = out;                        // 8388608
  float* out_idx    = out + 8388608;              // 256
  float* out_preq   = out_idx + 256;              // 262144
  float* out_quant  = out_preq + 262144;          // 262144
  float* out_loss   = out_quant + 262144;         // 2

  // Early scratch inside logits region (fully overwritten by dist_kernel later).
  float* part_pool = out_logits;                   // 64*32*1024 = 2097152 floats
  int*   cntpart   = (int*)(out_logits + 2097152); // 2048
  float* pooledT   = out_logits + 2099200;         // 32768
  int*   cnt       = (int*)(out_logits + 2131968); // 32

  // d_ws scratch (~1.6 MB)
  float* ws     = (float*)d_ws;
  float* xnorm  = ws;                              // 256
  float* pscore = ws + 256;                        // 256*256
  int*   pidx   = (int*)(ws + 256 + 65536);        // 256*256
  float* lsum   = ws + 131328;                     // 256
  unsigned short* A_img = (unsigned short*)(ws + 131584);  // 1 MB

  pool_kernel<<<dim3(B_, NCHUNK), 256, 0, stream>>>(hidden, mask, part_pool, cntpart);
  pool_reduce_kernel<<<128, 256, 0, stream>>>(part_pool, cntpart, pooledT, cnt);
  proj_kernel<<<256, 256, 0, stream>>>(Wp, pooledT, cnt, out_preq);
  aprep_kernel<<<ROWS, 256, 0, stream>>>(out_preq, A_img, xnorm);
  dist_kernel<<<NCB, 512, 0, stream>>>(A_img, codebook, xnorm, out_logits, pscore, pidx);
  finalize_kernel<<<ROWS, 256, 0, stream>>>(out_preq, codebook, pscore, pidx, out_idx, out_quant, lsum);
  loss_kernel<<<1, 256, 0, stream>>>(lsum, out_loss);
}

// Round 9
// 196.407 us; speedup vs baseline: 1.1494x; 1.0928x over previous
//
#include <hip/hip_runtime.h>
#include <hip/hip_bf16.h>

#define B_ 32
#define T_ 2048
#define H_ 1024
#define S_ 8
#define V_ 32768
#define ROWS 256    // B_*S_
#define OUTO 8192   // S_*H_
#define NCHUNK 64
#define TCHUNK 32
#define NCB 256     // dist col-blocks = V_/128
#define DELTA2 0.008f
#define MAXCAND 512

typedef __attribute__((ext_vector_type(8))) short s16x8;
typedef __attribute__((ext_vector_type(8))) unsigned short u16x8;
typedef __attribute__((ext_vector_type(4))) float f32x4;

// async global->LDS, 16B per lane (dest = wave-uniform base + lane*16)
__device__ __forceinline__ void gl_lds16(const void* gsrc, void* ldst) {
  __builtin_amdgcn_global_load_lds(
      (const __attribute__((address_space(1))) unsigned int*)gsrc,
      (__attribute__((address_space(3))) unsigned int*)ldst, 16, 0, 0);
}

__device__ __forceinline__ unsigned short bf16hi(float x) {
  return __builtin_bit_cast(unsigned short, __float2bfloat16(x));
}

// ---------------- kernel 1: masked pooling partials ----------------
__global__ void pool_kernel(const float* __restrict__ hidden,
                            const int* __restrict__ mask,
                            float* __restrict__ part_pool,   // [NCHUNK][B_][H_]
                            int* __restrict__ cntpart) {     // [NCHUNK][B_]
  int b = blockIdx.x;
  int chunk = blockIdx.y;
  int t0 = chunk * TCHUNK;
  int h4 = threadIdx.x * 4;
  const float* base = hidden + ((size_t)b * T_ + t0) * H_ + h4;
  const int* mrow = mask + (size_t)b * T_ + t0;
  float a0 = 0.f, a1 = 0.f, a2 = 0.f, a3 = 0.f;
  int mcount = 0;
#pragma unroll 4
  for (int i = 0; i < TCHUNK; ++i) {
    int mi = mrow[i];
    float m = (float)mi;
    mcount += mi;
    float4 v = *reinterpret_cast<const float4*>(base + (size_t)i * H_);
    a0 += m * v.x; a1 += m * v.y; a2 += m * v.z; a3 += m * v.w;
  }
  float* pp = part_pool + ((size_t)chunk * B_ + b) * H_ + h4;
  *reinterpret_cast<float4*>(pp) = make_float4(a0, a1, a2, a3);
  if (threadIdx.x == 0) cntpart[chunk * B_ + b] = mcount;
}

// ---------------- kernel 1b: reduce partials -> pooledT [h][b] ----------------
__global__ void pool_reduce_kernel(const float* __restrict__ part_pool,
                                   const int* __restrict__ cntpart,
                                   float* __restrict__ pooledT,
                                   int* __restrict__ cnt) {
  int g = blockIdx.x * 256 + threadIdx.x;   // g = b*1024 + h
  float s = 0.f;
  for (int c = 0; c < NCHUNK; ++c) s += part_pool[(size_t)c * (H_ * B_) + g];
  int b = g >> 10, h = g & 1023;
  pooledT[h * B_ + b] = s;
  if (g < B_) {
    int cs = 0;
    for (int c = 0; c < NCHUNK; ++c) cs += cntpart[c * B_ + g];
    cnt[g] = cs;
  }
}

// ---------------- kernel 2: pre_q = pooled @ W^T (LDS-staged pooled, 4 o/thread) ----------------
__global__ __launch_bounds__(256) void proj_kernel(const float* __restrict__ Wp,
                            const float* __restrict__ pooledT,
                            const int* __restrict__ cnt,
                            float* __restrict__ preq) {
  __shared__ float pl[32][516];
  const int t = threadIdx.x;
  const int og = t >> 5, b = t & 31;
  const int o0 = blockIdx.x * 32;
  float acc0 = 0.f, acc1 = 0.f, acc2 = 0.f, acc3 = 0.f;
  const float* wb = Wp + (size_t)(o0 + og * 4) * H_;
  for (int pass = 0; pass < 2; ++pass) {
    int k0 = pass * 512;
    __syncthreads();
#pragma unroll
    for (int i = 0; i < 16; ++i) {
      int f = i * 1024 + t * 4;            // 0..16383 over (k_local, b)
      int hl = f >> 5, b4 = f & 31;
      float4 v = *reinterpret_cast<const float4*>(&pooledT[(size_t)(k0 + hl) * 32 + b4]);
      pl[b4 + 0][hl] = v.x; pl[b4 + 1][hl] = v.y;
      pl[b4 + 2][hl] = v.z; pl[b4 + 3][hl] = v.w;
    }
    __syncthreads();
    const float* w0 = wb + k0;
#pragma unroll 4
    for (int j = 0; j < 128; ++j) {
      float4 p = *reinterpret_cast<const float4*>(&pl[b][4 * j]);
      float4 a = *reinterpret_cast<const float4*>(w0 + 4 * j);
      float4 c = *reinterpret_cast<const float4*>(w0 + H_ + 4 * j);
      float4 d = *reinterpret_cast<const float4*>(w0 + 2 * H_ + 4 * j);
      float4 e = *reinterpret_cast<const float4*>(w0 + 3 * H_ + 4 * j);
      acc0 += a.x * p.x + a.y * p.y + a.z * p.z + a.w * p.w;
      acc1 += c.x * p.x + c.y * p.y + c.z * p.z + c.w * p.w;
      acc2 += d.x * p.x + d.y * p.y + d.z * p.z + d.w * p.w;
      acc3 += e.x * p.x + e.y * p.y + e.z * p.z + e.w * p.w;
    }
  }
  float denom = fmaxf((float)cnt[b], 1.0f);
  size_t obase = (size_t)b * OUTO + o0 + og * 4;
  preq[obase + 0] = acc0 / denom;
  preq[obase + 1] = acc1 / denom;
  preq[obase + 2] = acc2 / denom;
  preq[obase + 3] = acc3 / denom;
}

// ---------------- kernel 2b: preq -> swizzled hi-bf16 image + xnorm ----------------
// A_img (ushort): [ks 0..31] { hi[256][32] } (8192 ushort = 16KB per ks),
// XOR-swizzled: ushort_idx ^= (row&7)<<3. dist reads with the same XOR.
__global__ void aprep_kernel(const float* __restrict__ preq,
                             unsigned short* __restrict__ A_img,
                             float* __restrict__ xnorm) {
  int row = blockIdx.x;
  int t = threadIdx.x;
  int k0 = 4 * t;
  int ks = k0 >> 5, kk = k0 & 31;
  float4 v = reinterpret_cast<const float4*>(preq + (size_t)row * H_)[t];
  float xv[4] = {v.x, v.y, v.z, v.w};
  unsigned short hv[4];
  float s = 0.f;
#pragma unroll
  for (int i = 0; i < 4; ++i) { s += xv[i] * xv[i]; hv[i] = bf16hi(xv[i]); }
  unsigned int sidx = (unsigned int)(row * 32 + kk) ^ (unsigned int)((row & 7) << 3);
  *reinterpret_cast<ushort4*>(&A_img[(size_t)ks * 8192 + sidx]) =
      make_ushort4(hv[0], hv[1], hv[2], hv[3]);
#pragma unroll
  for (int off = 1; off < 64; off <<= 1) s += __shfl_xor(s, off);
  __shared__ float ps[4];
  if ((t & 63) == 0) ps[t >> 6] = s;
  __syncthreads();
  if (t == 0) xnorm[row] = ps[0] + ps[1] + ps[2] + ps[3];
}

// ---------------- kernel 3: hi-only bf16 MFMA distance GEMM ----------------
// BM=256, BN=128, BK=32; 512 threads = 8 waves (4 row-groups x 2 col-halves), grid 256.
// Single hi*hi product (logit error <= ~1.6e-3 worst-case bound; argmax fixed by exact
// rescore in finalize). A: swizzled hi image via global_load_lds (dbuf). B: f32
// 2-step-deep reg prefetch (ra/rb) -> hi bf16 LDS (dbuf). One __syncthreads per K-step.
__global__ __launch_bounds__(512, 2) void dist_kernel(
    const unsigned short* __restrict__ A_img, const float* __restrict__ codebook,
    const float* __restrict__ xnorm, float* __restrict__ logits,
    float* __restrict__ pscore) {
  __shared__ __align__(16) unsigned short Asm[2][8192];     // 32 KB (swizzled hi image)
  __shared__ __align__(16) unsigned short Bs[2][128][40];   // 20 KB, pad 40
  __shared__ float cn[128];
  __shared__ float xns[256];
  __shared__ float bwv[2][256];

  const int t = threadIdx.x;        // 0..511
  const int l = t & 63;
  const int w = t >> 6;             // wave 0..7
  const int cb = w & 1;             // col half
  const int m0 = (w >> 1) * 64;     // row group
  const int lr = l & 15, lq = l >> 4;
  const int blk = blockIdx.x;
  const int v0 = blk * 128;

  if (t < 256) xns[t] = xnorm[t];

  const int sn = t >> 2;            // staged codebook row 0..127
  const int sk = (t & 3) * 8;       // k offset within 32
  const float* cbp = codebook + (size_t)(v0 + sn) * H_ + sk;
  float csq = 0.f;

  f32x4 acc[4][4];
#pragma unroll
  for (int i = 0; i < 4; ++i)
#pragma unroll
    for (int j = 0; j < 4; ++j) acc[i][j] = (f32x4){0.f, 0.f, 0.f, 0.f};

  const char* Abase = (const char*)A_img;

  unsigned int aoff[4];
#pragma unroll
  for (int mt = 0; mt < 4; ++mt) {
    int row = m0 + mt * 16 + lr;
    aoff[mt] = (unsigned int)(row * 32 + lq * 8) ^ (unsigned int)((row & 7) << 3);
  }

#define CONVERT_TO(BUF, X0, X1)                                                   \
  {                                                                               \
    float xv[8] = {X0.x, X0.y, X0.z, X0.w, X1.x, X1.y, X1.z, X1.w};               \
    u16x8 hv;                                                                     \
    _Pragma("unroll")                                                             \
    for (int i = 0; i < 8; ++i) { float x = xv[i]; csq += x * x; hv[i] = bf16hi(x); } \
    *reinterpret_cast<u16x8*>(&Bs[BUF][sn][sk]) = hv;                             \
  }

#define STAGE_A(KS, BUF)                                                          \
  _Pragma("unroll")                                                               \
  for (int j = 0; j < 2; ++j) {                                                   \
    int c = w * 2 + j;                                                            \
    gl_lds16(Abase + (size_t)(KS) * 16384 + (size_t)c * 1024 + (size_t)l * 16,    \
             &Asm[BUF][c * 512]);                                                 \
  }

  // Step KS: stage A(KS+1); load cb(KS+2)->RT; frags+MFMA(cur); convert RS(=cb(KS+1))
  // -> Bs[nxt]; one barrier. RT loads get MFMA+convert time (~full step) in flight.
#define DIST_STEP(KS, RT0, RT1, RS0, RS1)                                         \
  {                                                                               \
    const int curb = (KS) & 1, nxt = curb ^ 1;                                    \
    if ((KS) < 31) STAGE_A((KS) + 1, nxt);                                        \
    if ((KS) < 30) {                                                              \
      RT0 = *reinterpret_cast<const float4*>(cbp + ((KS) + 2) * 32);              \
      RT1 = *reinterpret_cast<const float4*>(cbp + ((KS) + 2) * 32 + 4);          \
    }                                                                             \
    s16x8 ah[4], bh[4];                                                           \
    _Pragma("unroll")                                                             \
    for (int nt = 0; nt < 4; ++nt)                                                \
      bh[nt] = *reinterpret_cast<const s16x8*>(&Bs[curb][cb * 64 + nt * 16 + lr][lq * 8]); \
    _Pragma("unroll")                                                             \
    for (int mt = 0; mt < 4; ++mt)                                                \
      ah[mt] = *reinterpret_cast<const s16x8*>(&Asm[curb][aoff[mt]]);             \
    __builtin_amdgcn_s_setprio(1);                                                \
    _Pragma("unroll")                                                             \
    for (int mt = 0; mt < 4; ++mt)                                                \
      _Pragma("unroll")                                                           \
      for (int nt = 0; nt < 4; ++nt)                                              \
        acc[mt][nt] = __builtin_amdgcn_mfma_f32_16x16x32_bf16(ah[mt], bh[nt], acc[mt][nt], 0, 0, 0); \
    __builtin_amdgcn_s_setprio(0);                                                \
    if ((KS) < 31) CONVERT_TO(nxt, RS0, RS1);                                     \
    __syncthreads();                                                              \
  }

  // ---- prologue: A(0) staged; cb(0)->ra converted to Bs[0]; cb(1)->rb in regs ----
  STAGE_A(0, 0);
  float4 ra0 = *reinterpret_cast<const float4*>(cbp);
  float4 ra1 = *reinterpret_cast<const float4*>(cbp + 4);
  float4 rb0 = *reinterpret_cast<const float4*>(cbp + 32);
  float4 rb1 = *reinterpret_cast<const float4*>(cbp + 36);
  CONVERT_TO(0, ra0, ra1);
  __syncthreads();

  // ---- main loop: ra/rb rotation (even step loads->ra, converts rb; odd vice versa) ----
#pragma unroll 1
  for (int ks = 0; ks < 32; ks += 2) {
    DIST_STEP(ks,     ra0, ra1, rb0, rb1);
    DIST_STEP(ks + 1, rb0, rb1, ra0, ra1);
  }

  // ||c||^2: reduce the 4 k-offset threads (consecutive lanes) of each staged row
  csq += __shfl_xor(csq, 1);
  csq += __shfl_xor(csq, 2);
  if ((t & 3) == 0) cn[sn] = csq;
  __syncthreads();

  // epilogue: logits + per-row approx max over this block's 128 cols
  const float NEG = -3.402823466e38f;
#pragma unroll
  for (int mt = 0; mt < 4; ++mt) {
#pragma unroll
    for (int r = 0; r < 4; ++r) {
      int row = m0 + mt * 16 + lq * 4 + r;
      float xn = xns[row];
      float bs = NEG;
#pragma unroll
      for (int nt = 0; nt < 4; ++nt) {
        int col = cb * 64 + nt * 16 + lr;
        float sc = 2.f * acc[mt][nt][r] - cn[col];
        logits[(size_t)row * V_ + v0 + col] = sc - xn;
        bs = fmaxf(bs, sc);
      }
#pragma unroll
      for (int off = 1; off < 16; off <<= 1) bs = fmaxf(bs, __shfl_xor(bs, off));
      if (lr == 0) bwv[cb][row] = bs;
    }
  }
  __syncthreads();
  if (t < 256) pscore[(size_t)t * NCB + blk] = fmaxf(bwv[0][t], bwv[1][t]);
}

// ---------------- kernel 4: candidate collection + exact f64 rescore + gather/loss ----------------
__global__ __launch_bounds__(256) void finalize_kernel(
    const float* __restrict__ preq, const float* __restrict__ codebook,
    const float* __restrict__ logits, const float* __restrict__ xnorm,
    const float* __restrict__ pscore,
    float* __restrict__ out_idx, float* __restrict__ out_quant,
    float* __restrict__ lsum) {
  int row = blockIdx.x;
  int t = threadIdx.x;
  // 1) global approx max M over 256 block maxima (scores sc = 2*dot_hh - cn)
  float m = pscore[(size_t)row * NCB + t];
#pragma unroll
  for (int off = 1; off < 64; off <<= 1) m = fmaxf(m, __shfl_xor(m, off));
  __shared__ float wm[4];
  if ((t & 63) == 0) wm[t >> 6] = m;
  __syncthreads();
  float M = fmaxf(fmaxf(wm[0], wm[1]), fmaxf(wm[2], wm[3]));
  float thr = M - xnorm[row] - DELTA2;   // logit-space threshold
  __shared__ int cand[MAXCAND];
  __shared__ int ncand;
  if (t == 0) ncand = 0;
  __syncthreads();
  // 2) scan this row's 32768 logits for candidates within DELTA2 of the max
  const float* lrow = logits + (size_t)row * V_;
#pragma unroll 4
  for (int it = 0; it < 32; ++it) {
    int c0 = it * 1024 + t * 4;
    float4 lg = *reinterpret_cast<const float4*>(lrow + c0);
    if (lg.x >= thr) { int p = atomicAdd(&ncand, 1); if (p < MAXCAND) cand[p] = c0; }
    if (lg.y >= thr) { int p = atomicAdd(&ncand, 1); if (p < MAXCAND) cand[p] = c0 + 1; }
    if (lg.z >= thr) { int p = atomicAdd(&ncand, 1); if (p < MAXCAND) cand[p] = c0 + 2; }
    if (lg.w >= thr) { int p = atomicAdd(&ncand, 1); if (p < MAXCAND) cand[p] = c0 + 3; }
  }
  __syncthreads();
  int total = ncand;
  const float* pr = preq + (size_t)row * H_;
  int idx;
  if (total <= MAXCAND) {
    // 3a) exact rescore in double: s = sum_k c_k*(2*x_k - c_k); max, lowest-idx ties
    __shared__ double sd[4];
    double best = -1.0e300; int bi = V_;
    for (int j = 0; j < total; ++j) {
      int c = cand[j];
      const float* cr = codebook + (size_t)c * H_;
      float4 cv = reinterpret_cast<const float4*>(cr)[t];
      float4 pv = reinterpret_cast<const float4*>(pr)[t];
      double p = (double)cv.x * (2.0 * (double)pv.x - (double)cv.x)
               + (double)cv.y * (2.0 * (double)pv.y - (double)cv.y)
               + (double)cv.z * (2.0 * (double)pv.z - (double)cv.z)
               + (double)cv.w * (2.0 * (double)pv.w - (double)cv.w);
#pragma unroll
      for (int off = 1; off < 64; off <<= 1) p += __shfl_xor(p, off);
      if ((t & 63) == 0) sd[t >> 6] = p;
      __syncthreads();
      double s = sd[0] + sd[1] + sd[2] + sd[3];   // identical on all threads
      if (s > best || (s == best && c < bi)) { best = s; bi = c; }
      __syncthreads();
    }
    idx = bi;
  } else {
    // 3b) deterministic full-scan fallback (not expected to trigger)
    double best = -1.0e300; int bi = V_;
    for (int c = t; c < V_; c += 256) {
      const float* cr = codebook + (size_t)c * H_;
      double s = 0.0;
      for (int k = 0; k < H_; k += 4) {
        float4 cv = *reinterpret_cast<const float4*>(cr + k);
        float4 pv = *reinterpret_cast<const float4*>(pr + k);
        s += (double)cv.x * (2.0 * (double)pv.x - (double)cv.x)
           + (double)cv.y * (2.0 * (double)pv.y - (double)cv.y)
           + (double)cv.z * (2.0 * (double)pv.z - (double)cv.z)
           + (double)cv.w * (2.0 * (double)pv.w - (double)cv.w);
      }
      if (s > best || (s == best && c < bi)) { best = s; bi = c; }
    }
#pragma unroll
    for (int off = 1; off < 64; off <<= 1) {
      double os = __shfl_xor(best, off);
      int oi = __shfl_xor(bi, off);
      if (os > best || (os == best && oi < bi)) { best = os; bi = oi; }
    }
    __shared__ double fb[4]; __shared__ int fbi[4];
    if ((t & 63) == 0) { fb[t >> 6] = best; fbi[t >> 6] = bi; }
    __syncthreads();
    double b0 = fb[0]; int i0 = fbi[0];
    for (int wv = 1; wv < 4; ++wv)
      if (fb[wv] > b0 || (fb[wv] == b0 && fbi[wv] < i0)) { b0 = fb[wv]; i0 = fbi[wv]; }
    idx = i0;
  }
  if (t == 0) out_idx[row] = (float)idx;
  // 4) gather, quantize, loss partial
  float4 e = reinterpret_cast<const float4*>(codebook + (size_t)idx * H_)[t];
  float4 p4 = reinterpret_cast<const float4*>(pr)[t];
  float4 q;
  q.x = p4.x + (e.x - p4.x); q.y = p4.y + (e.y - p4.y);
  q.z = p4.z + (e.z - p4.z); q.w = p4.w + (e.w - p4.w);
  reinterpret_cast<float4*>(out_quant)[row * 256 + t] = q;
  float dx = p4.x - e.x, dy = p4.y - e.y, dz = p4.z - e.z, dw = p4.w - e.w;
  float ls = dx * dx + dy * dy + dz * dz + dw * dw;
#pragma unroll
  for (int off = 1; off < 64; off <<= 1) ls += __shfl_xor(ls, off);
  __shared__ float lss[4];
  if ((t & 63) == 0) lss[t >> 6] = ls;
  __syncthreads();
  if (t == 0) lsum[row] = lss[0] + lss[1] + lss[2] + lss[3];
}

// ---------------- kernel 5: final losses ----------------
__global__ void loss_kernel(const float* __restrict__ lsum, float* __restrict__ out_loss) {
  int t = threadIdx.x;
  float s = lsum[t];
#pragma unroll
  for (int off = 1; off < 64; off <<= 1) s += __shfl_xor(s, off);
  __shared__ float a[4];
  if ((t & 63) == 0) a[t >> 6] = s;
  __syncthreads();
  if (t == 0) {
    float lv = (a[0] + a[1] + a[2] + a[3]) / (float)(ROWS * H_);
    out_loss[0] = lv; out_loss[1] = lv;
  }
}

extern "C" void kernel_launch(void* const* d_in, const int* in_sizes, int n_in,
                              void* d_out, int out_size, void* d_ws, size_t ws_size,
                              hipStream_t stream) {
  (void)in_sizes; (void)n_in; (void)out_size; (void)ws_size;
  const float* hidden   = (const float*)d_in[0];
  const int* mask       = (const int*)d_in[1];
  const float* Wp       = (const float*)d_in[2];
  const float* codebook = (const float*)d_in[3];

  float* out = (float*)d_out;
  float* out_logits = out;                        // 8388608
  float* out_idx    = out + 8388608;              // 256
  float* out_preq   = out_idx + 256;              // 262144
  float* out_quant  = out_preq + 262144;          // 262144
  float* out_loss   = out_quant + 262144;         // 2

  // Early scratch inside logits region (fully overwritten by dist_kernel later).
  float* part_pool = out_logits;                   // 64*32*1024 = 2097152 floats
  int*   cntpart   = (int*)(out_logits + 2097152); // 2048
  float* pooledT   = out_logits + 2099200;         // 32768
  int*   cnt       = (int*)(out_logits + 2131968); // 32

  // d_ws scratch (~0.8 MB)
  float* ws     = (float*)d_ws;
  float* xnorm  = ws;                              // 256
  float* pscore = ws + 256;                        // 256*256
  float* lsum   = ws + 65792;                      // 256
  unsigned short* A_img = (unsigned short*)(ws + 66048);   // 512 KB

  pool_kernel<<<dim3(B_, NCHUNK), 256, 0, stream>>>(hidden, mask, part_pool, cntpart);
  pool_reduce_kernel<<<128, 256, 0, stream>>>(part_pool, cntpart, pooledT, cnt);
  proj_kernel<<<256, 256, 0, stream>>>(Wp, pooledT, cnt, out_preq);
  aprep_kernel<<<ROWS, 256, 0, stream>>>(out_preq, A_img, xnorm);
  dist_kernel<<<NCB, 512, 0, stream>>>(A_img, codebook, xnorm, out_logits, pscore);
  finalize_kernel<<<ROWS, 256, 0, stream>>>(out_preq, codebook, out_logits, xnorm,
                                            pscore, out_idx, out_quant, lsum);
  loss_kernel<<<1, 256, 0, stream>>>(lsum, out_loss);
}